// Round 2
// baseline (42.637 us; speedup 1.0000x reference)
//
#include <hip/hip_runtime.h>
#include <float.h>

// ROI adaptive max pool 7x7 over top-left h[n] x w[n] region of 14x14 planes.
// N=512, C=256, HMAX=WMAX=14, OUT=7.
// start = floor(i*L/7), end = ceil((i+1)*L/7): bins OVERLAP and span 1..3
// elements per dim (width <= (L+12)/7 < 4 for L<=14). Branchless 3x3-point
// max with duplicated middle/corner indices covers all widths.

constexpr int N_   = 512;
constexpr int C_   = 256;
constexpr int HMAX = 14;
constexpr int WMAX = 14;
constexpr int OUT  = 7;
constexpr int PLANE = HMAX * WMAX;              // 196
constexpr int TOTAL = N_ * C_ * OUT * OUT;      // 6,422,528

__global__ __launch_bounds__(256) void roipool_kernel(
    const float* __restrict__ rois,
    const int*   __restrict__ h,
    const int*   __restrict__ w,
    float*       __restrict__ out)
{
    int idx = blockIdx.x * 256 + threadIdx.x;
    if (idx >= TOTAL) return;

    int q     = idx % 49;          // output position within plane
    int plane = idx / 49;          // n*C + c
    int n     = plane / C_;
    int i     = q / 7;             // output row
    int j     = q % 7;             // output col

    int Lh = h[n];
    int Lw = w[n];

    // bin bounds: start = floor(i*L/7), end = ceil((i+1)*L/7); width 1..3.
    int sh = (i * Lh) / 7;
    int eh = ((i + 1) * Lh + 6) / 7;   // exclusive
    int sw = (j * Lw) / 7;
    int ew = ((j + 1) * Lw + 6) / 7;   // exclusive

    int r1 = sh, r3 = eh - 1, r2 = min(sh + 1, r3);
    int c1 = sw, c3 = ew - 1, c2 = min(sw + 1, c3);

    const float* base = rois + (long long)plane * PLANE;
    const float* row1 = base + r1 * WMAX;
    const float* row2 = base + r2 * WMAX;
    const float* row3 = base + r3 * WMAX;

    float m = row1[c1];
    m = fmaxf(m, row1[c2]);
    m = fmaxf(m, row1[c3]);
    m = fmaxf(m, row2[c1]);
    m = fmaxf(m, row2[c2]);
    m = fmaxf(m, row2[c3]);
    m = fmaxf(m, row3[c1]);
    m = fmaxf(m, row3[c2]);
    m = fmaxf(m, row3[c3]);

    out[idx] = m;
}

extern "C" void kernel_launch(void* const* d_in, const int* in_sizes, int n_in,
                              void* d_out, int out_size, void* d_ws, size_t ws_size,
                              hipStream_t stream)
{
    const float* rois = (const float*)d_in[0];
    const int*   h    = (const int*)d_in[1];
    const int*   w    = (const int*)d_in[2];
    float*       out  = (float*)d_out;

    int blocks = (TOTAL + 255) / 256;
    roipool_kernel<<<blocks, 256, 0, stream>>>(rois, h, w, out);
}

// Round 3
// 26.157 us; speedup vs baseline: 1.6301x; 1.6301x over previous
//
#include <hip/hip_runtime.h>
#include <float.h>

// ROI adaptive max pool 7x7 over top-left h[n] x w[n] region of 14x14 planes.
// N=512, C=256, HMAX=WMAX=14, OUT=7. Bin widths are 1..3 per dim -> branchless
// 3x3-point max with duplicated indices.
//
// Round-2 lesson: direct per-thread 4B gathers were L1-request-bound (63us,
// HBM 14%). This version stages 16 planes/block into LDS via coalesced float4
// loads; the 9-point scatter hits LDS instead of L1. All 16 planes in a block
// belong to the same image n (256 planes/image, 16 | 256), so h[n]/w[n] are
// block-uniform.

constexpr int N_   = 512;
constexpr int C_   = 256;
constexpr int HMAX = 14;
constexpr int WMAX = 14;
constexpr int OUT  = 7;
constexpr int PLANE = HMAX * WMAX;              // 196 floats
constexpr int P     = 16;                       // planes per block
constexpr int NBLK  = (N_ * C_) / P;            // 8192 blocks
constexpr int LDSF  = P * PLANE;                // 3136 floats = 12544 B
constexpr int NV4   = LDSF / 4;                 // 784 float4 loads
constexpr int NOUT  = P * OUT * OUT;            // 784 outputs per block

__global__ __launch_bounds__(256) void roipool_kernel(
    const float* __restrict__ rois,
    const int*   __restrict__ h,
    const int*   __restrict__ w,
    float*       __restrict__ out)
{
    __shared__ float lds[LDSF];

    const int tid  = threadIdx.x;
    const int blk  = blockIdx.x;

    // ---- stage 16 planes, fully coalesced float4 ----
    const float4* src = (const float4*)(rois + (size_t)blk * LDSF);
    float4* dst = (float4*)lds;
    #pragma unroll
    for (int k = 0; k < 4; ++k) {              // 4*256 = 1024 >= 784
        int idx = tid + k * 256;
        if (idx < NV4) dst[idx] = src[idx];
    }

    // block-uniform ROI size
    const int n  = blk >> 4;                   // 16 blocks per image
    const int Lh = h[n];
    const int Lw = w[n];
    __syncthreads();

    // ---- compute 784 outputs, coalesced stores ----
    float* outb = out + (size_t)blk * NOUT;
    #pragma unroll
    for (int k = 0; k < 4; ++k) {
        int o = tid + k * 256;
        if (o >= NOUT) break;
        int p = o / 49;
        int q = o - p * 49;
        int i = q / 7;
        int j = q - i * 7;

        int sh = (i * Lh) / 7;
        int eh = ((i + 1) * Lh + 6) / 7;       // exclusive
        int sw = (j * Lw) / 7;
        int ew = ((j + 1) * Lw + 6) / 7;       // exclusive

        int r1 = sh, r3 = eh - 1, r2 = min(sh + 1, r3);
        int c1 = sw, c3 = ew - 1, c2 = min(sw + 1, c3);

        const float* base = lds + p * PLANE;
        const float* row1 = base + r1 * WMAX;
        const float* row2 = base + r2 * WMAX;
        const float* row3 = base + r3 * WMAX;

        float m = row1[c1];
        m = fmaxf(m, row1[c2]);
        m = fmaxf(m, row1[c3]);
        m = fmaxf(m, row2[c1]);
        m = fmaxf(m, row2[c2]);
        m = fmaxf(m, row2[c3]);
        m = fmaxf(m, row3[c1]);
        m = fmaxf(m, row3[c2]);
        m = fmaxf(m, row3[c3]);

        outb[o] = m;
    }
}

extern "C" void kernel_launch(void* const* d_in, const int* in_sizes, int n_in,
                              void* d_out, int out_size, void* d_ws, size_t ws_size,
                              hipStream_t stream)
{
    const float* rois = (const float*)d_in[0];
    const int*   h    = (const int*)d_in[1];
    const int*   w    = (const int*)d_in[2];
    float*       out  = (float*)d_out;

    roipool_kernel<<<NBLK, 256, 0, stream>>>(rois, h, w, out);
}

// Round 4
// 24.613 us; speedup vs baseline: 1.7323x; 1.0627x over previous
//
#include <hip/hip_runtime.h>
#include <float.h>

// ROI adaptive max pool 7x7 over top-left h[n] x w[n] region of 14x14 planes.
// N=512, C=256, HMAX=WMAX=14, OUT=7. Bin widths 1..3 per dim -> branchless
// 3x3-point max with duplicated indices.
//
// Round-3 lesson: LDS staging fixed the L1-gather bound (63->26us). Now cut
// read traffic: bins only ever touch rows 0..Lh-1 (max row = Lh-1), and Lh is
// block-uniform (16 planes/block all share image n). Stage only the first
// ceil(3.5*Lh) float4s of each plane: avg read 103MB -> 78MB.

constexpr int N_   = 512;
constexpr int C_   = 256;
constexpr int HMAX = 14;
constexpr int WMAX = 14;
constexpr int OUT  = 7;
constexpr int PLANE = HMAX * WMAX;              // 196 floats (= 49 float4)
constexpr int P     = 16;                       // planes per block
constexpr int NBLK  = (N_ * C_) / P;            // 8192 blocks
constexpr int NOUT  = P * OUT * OUT;            // 784 outputs per block

__global__ __launch_bounds__(256) void roipool_kernel(
    const float* __restrict__ rois,
    const int*   __restrict__ h,
    const int*   __restrict__ w,
    float*       __restrict__ out)
{
    __shared__ float lds[P * PLANE];

    const int tid = threadIdx.x;
    const int blk = blockIdx.x;

    // block-uniform ROI size (16 blocks per image, scalar loads)
    const int n  = blk >> 4;
    const int Lh = h[n];
    const int Lw = w[n];
    const int V  = (7 * Lh + 1) >> 1;          // float4s per plane actually used
                                               // (covers floats [0, 14*Lh) .. +2)

    // ---- stage: 16 threads per plane, 256B contiguous chunks, rows >= Lh skipped
    {
        const float4* src = (const float4*)rois + (size_t)blk * (NOUT);
        float4* ldsv = (float4*)lds;
        int p = tid >> 4;
        int l = tid & 15;
        int base = p * 49;                     // plane stride = 49 float4
        for (int v = l; v < V; v += 16)
            ldsv[base + v] = src[base + v];
    }
    __syncthreads();

    // ---- compute: 196 threads x 4 outputs, float4 store ----
    if (tid < 196) {
        float m[4];
        const int o0 = tid * 4;
        #pragma unroll
        for (int u = 0; u < 4; ++u) {
            int o = o0 + u;
            int p = o / 49;                    // compile-time magic
            int q = o - p * 49;
            int i = q / 7;
            int j = q - i * 7;

            // exact /7 for x <= 104: (x*147)>>10
            int th = i * Lh;
            int tw = j * Lw;
            int r1 = (th * 147) >> 10;
            int r3 = (((th + Lh + 6) * 147) >> 10) - 1;   // ceil((i+1)Lh/7)-1
            int r2 = min(r1 + 1, r3);
            int c1 = (tw * 147) >> 10;
            int c3 = (((tw + Lw + 6) * 147) >> 10) - 1;
            int c2 = min(c1 + 1, c3);

            const float* base = lds + p * PLANE;
            const float* row1 = base + r1 * WMAX;
            const float* row2 = base + r2 * WMAX;
            const float* row3 = base + r3 * WMAX;

            float v0 = fmaxf(fmaxf(row1[c1], row1[c2]), row1[c3]);
            float v1 = fmaxf(fmaxf(row2[c1], row2[c2]), row2[c3]);
            float v2 = fmaxf(fmaxf(row3[c1], row3[c2]), row3[c3]);
            m[u] = fmaxf(fmaxf(v0, v1), v2);
        }
        float4 res = make_float4(m[0], m[1], m[2], m[3]);
        ((float4*)out)[(size_t)blk * (NOUT / 4) + tid] = res;
    }
}

extern "C" void kernel_launch(void* const* d_in, const int* in_sizes, int n_in,
                              void* d_out, int out_size, void* d_ws, size_t ws_size,
                              hipStream_t stream)
{
    const float* rois = (const float*)d_in[0];
    const int*   h    = (const int*)d_in[1];
    const int*   w    = (const int*)d_in[2];
    float*       out  = (float*)d_out;

    roipool_kernel<<<NBLK, 256, 0, stream>>>(rois, h, w, out);
}